// Round 1
// baseline (605.031 us; speedup 1.0000x reference)
//
#include <hip/hip_runtime.h>
#include <stdint.h>

#define NLEVELS 16
#define BLOCK 256

__global__ __launch_bounds__(BLOCK) void hashgrid_encode_kernel(
    const float* __restrict__ xyz,
    const float* __restrict__ emb,
    const float* __restrict__ minv,
    const float* __restrict__ maxv,
    float* __restrict__ out,
    int B)
{
    constexpr int RES[NLEVELS] = {16, 22, 30, 42, 58, 80, 111, 154,
                                  212, 294, 406, 561, 776, 1072, 1482, 2048};
    // transpose buffer: 32 feature rows x (BLOCK+1) points; +1 pad -> stride 257 (mod 32 == 1)
    __shared__ float s[32][BLOCK + 1];

    const int t = threadIdx.x;
    const int pt = blockIdx.x * BLOCK + t;

    // uniform scalar params (compiler emits s_loads)
    const float mn0 = minv[0], mn1 = minv[1], mn2 = minv[2];
    const float inv0 = 1.0f / (maxv[0] - mn0);
    const float inv1 = 1.0f / (maxv[1] - mn1);
    const float inv2 = 1.0f / (maxv[2] - mn2);

    float nx = 0.0f, ny = 0.0f, nz = 0.0f;
    bool valid = false;
    if (pt < B) {
        const float x = xyz[3 * pt + 0];
        const float y = xyz[3 * pt + 1];
        const float z = xyz[3 * pt + 2];
        nx = (x - mn0) * inv0;
        ny = (y - mn1) * inv1;
        nz = (z - mn2) * inv2;
        valid = (nx >= 0.0f) && (nx <= 1.0f) &&
                (ny >= 0.0f) && (ny <= 1.0f) &&
                (nz >= 0.0f) && (nz <= 1.0f);
    }

    #pragma unroll
    for (int l = 0; l < NLEVELS; ++l) {
        const int r = RES[l];
        const float rm1 = (float)(r - 1);

        const float px = nx * rm1;
        const float py = ny * rm1;
        const float pz = nz * rm1;

        int fx = (int)floorf(px); fx = min(max(fx, 0), r - 2);
        int fy = (int)floorf(py); fy = min(max(fy, 0), r - 2);
        int fz = (int)floorf(pz); fz = min(max(fz, 0), r - 2);

        const float fracx = px - (float)fx;
        const float fracy = py - (float)fy;
        const float fracz = pz - (float)fz;

        // per-axis hashes for both corner coords (primes[0] == 1)
        const uint32_t hx0 = (uint32_t)fx;
        const uint32_t hx1 = hx0 + 1u;
        const uint32_t hy0 = (uint32_t)fy * 2654435761u;
        const uint32_t hy1 = hy0 + 2654435761u;
        const uint32_t hz0 = (uint32_t)fz * 805459861u;
        const uint32_t hz1 = hz0 + 805459861u;

        const uint32_t basei = (uint32_t)l << 19;   // l * 524288

        const float wx1 = fracx, wx0 = 1.0f - fracx;
        const float wy1 = fracy, wy0 = 1.0f - fracy;
        const float wz1 = fracz, wz0 = 1.0f - fracz;

        float acc0 = 0.0f, acc1 = 0.0f;
        #pragma unroll
        for (int c = 0; c < 8; ++c) {
            const uint32_t h = ((c & 1) ? hx1 : hx0) ^
                               ((c & 2) ? hy1 : hy0) ^
                               ((c & 4) ? hz1 : hz0);
            const uint32_t idx = basei + (h & 0x7FFFFu);
            const float2 f = *reinterpret_cast<const float2*>(emb + ((size_t)idx << 1));
            const float w = ((c & 1) ? wx1 : wx0) *
                            ((c & 2) ? wy1 : wy0) *
                            ((c & 4) ? wz1 : wz0);
            acc0 = fmaf(w, f.x, acc0);
            acc1 = fmaf(w, f.y, acc1);
        }
        s[2 * l + 0][t] = valid ? acc0 : 0.0f;
        s[2 * l + 1][t] = valid ? acc1 : 0.0f;
    }

    __syncthreads();

    // coalesced writeout of this block's contiguous (BLOCK*32)-float chunk
    const size_t chunk = (size_t)blockIdx.x * (BLOCK * 32);
    const size_t total = (size_t)B * 32;
    #pragma unroll
    for (int k = 0; k < 32; ++k) {
        const int flat = k * BLOCK + t;           // 0 .. BLOCK*32-1
        const int p = flat >> 5;                  // point within block
        const int c = flat & 31;                  // feature index
        const size_t g = chunk + (size_t)flat;
        if (g < total) out[g] = s[c][p];
    }
}

extern "C" void kernel_launch(void* const* d_in, const int* in_sizes, int n_in,
                              void* d_out, int out_size, void* d_ws, size_t ws_size,
                              hipStream_t stream) {
    const float* xyz = (const float*)d_in[0];
    const float* emb = (const float*)d_in[1];
    const float* mn  = (const float*)d_in[2];
    const float* mx  = (const float*)d_in[3];
    float* out = (float*)d_out;

    const int B = in_sizes[0] / 3;
    const int blocks = (B + BLOCK - 1) / BLOCK;

    hipLaunchKernelGGL(hashgrid_encode_kernel, dim3(blocks), dim3(BLOCK), 0, stream,
                       xyz, emb, mn, mx, out, B);
}